// Round 6
// baseline (552.507 us; speedup 1.0000x reference)
//
#include <hip/hip_runtime.h>
#include <cstdint>
#include <cstddef>

#define NNODES 100000
#define NEDGES 1600000
#define INCH   128
#define HID    128
#define NCLS   40
#define NCOMM_ 1000

#define NBLK  128                 // partition blocks for bucket sort
#define EPB   (NEDGES/NBLK)       // 12500 edges per block (exact)
#define NBUCK ((NNODES+255)/256)  // 391 buckets of 256 nodes
#define NCNT  (NBLK*NBUCK)

typedef unsigned int uint32;
typedef unsigned short ushort16;
typedef short s16x8 __attribute__((ext_vector_type(8)));
typedef float f32x4 __attribute__((ext_vector_type(4)));

static __device__ __forceinline__ float4 ld4(const float* p){ return *reinterpret_cast<const float4*>(p); }

// f32 -> bf16 (RTN-even) and back, via bit ops
static __device__ __forceinline__ unsigned short f2b(float f){
  union{float f; uint32 u;} v; v.f=f;
  uint32 r = v.u + 0x7fffu + ((v.u>>16)&1u);
  return (unsigned short)(r>>16);
}
static __device__ __forceinline__ float b2f(unsigned short h){
  union{uint32 u; float f;} v; v.u = ((uint32)h)<<16; return v.f;
}
static __device__ __forceinline__ float lo16f(uint32 u){ return __int_as_float((int)(u<<16)); }
static __device__ __forceinline__ float hi16f(uint32 u){ return __int_as_float((int)(u&0xffff0000u)); }

static __device__ __forceinline__ void acc8(float* a, uint4 v, float nr){
  a[0]=fmaf(lo16f(v.x),nr,a[0]); a[1]=fmaf(hi16f(v.x),nr,a[1]);
  a[2]=fmaf(lo16f(v.y),nr,a[2]); a[3]=fmaf(hi16f(v.y),nr,a[3]);
  a[4]=fmaf(lo16f(v.z),nr,a[4]); a[5]=fmaf(hi16f(v.z),nr,a[5]);
  a[6]=fmaf(lo16f(v.w),nr,a[6]); a[7]=fmaf(hi16f(v.w),nr,a[7]);
}
static __device__ __forceinline__ void acc4(float* a, uint2 v, float nr){
  a[0]=fmaf(lo16f(v.x),nr,a[0]); a[1]=fmaf(hi16f(v.x),nr,a[1]);
  a[2]=fmaf(lo16f(v.y),nr,a[2]); a[3]=fmaf(hi16f(v.y),nr,a[3]);
}

// ---------------- community counting (atomics; only 100K over 1000 bins) ----------------
__global__ void k_ccomm(const int* __restrict__ comm, int* __restrict__ ccnt){
  int i=blockIdx.x*blockDim.x+threadIdx.x;
  if(i<NNODES) atomicAdd(&ccnt[comm[i]],1);
}

// ---------------- bucket sort pass A: per-block LDS histogram over dst>>8 ----------------
__global__ __launch_bounds__(256) void k_bcnt(const int* __restrict__ ei, int* __restrict__ cnt){
  __shared__ int h[NBUCK];
  int t=threadIdx.x, blk=blockIdx.x;
  for(int i=t;i<NBUCK;i+=256) h[i]=0;
  __syncthreads();
  int base=blk*EPB;
  for(int j=t;j<EPB;j+=256){
    int d=ei[NEDGES+base+j];
    atomicAdd(&h[d>>8],1);
  }
  __syncthreads();
  for(int i=t;i<NBUCK;i+=256) cnt[i*NBLK+blk]=h[i];
}

// ---------------- bucket sort pass B: exclusive scan of cnt (bucket-major), bucket bases ----------------
__global__ __launch_bounds__(1024) void k_bscan(int* __restrict__ cnt, int* __restrict__ brow,
                                                int* __restrict__ rp){
  __shared__ int sm[1024];
  int t=threadIdx.x;
  const int span=(NCNT+1023)/1024;   // 49
  int base=t*span;
  int s=0;
  for(int j=0;j<span;j++){ int i=base+j; if(i<NCNT) s+=cnt[i]; }
  sm[t]=s; __syncthreads();
  #pragma unroll
  for(int off=1;off<1024;off<<=1){
    int u=(t>=off)?sm[t-off]:0;
    __syncthreads();
    sm[t]+=u;
    __syncthreads();
  }
  int run=(t==0)?0:sm[t-1];
  for(int j=0;j<span;j++){
    int i=base+j;
    if(i<NCNT){
      int c=cnt[i];
      cnt[i]=run;
      if((i&(NBLK-1))==0) brow[i/NBLK]=run;
      run+=c;
    }
  }
  if(t==1023){ brow[NBUCK]=NEDGES; rp[NNODES]=NEDGES; }
}

// ---------------- bucket sort pass C: deterministic scatter into bucket-partitioned ebuf ----------------
__global__ __launch_bounds__(256) void k_bscatter(const int* __restrict__ ei, const int* __restrict__ cnt,
                                                  int2* __restrict__ ebuf){
  __shared__ int offs[NBUCK];
  int t=threadIdx.x, blk=blockIdx.x;
  for(int i=t;i<NBUCK;i+=256) offs[i]=cnt[i*NBLK+blk];
  __syncthreads();
  int base=blk*EPB;
  for(int j=t;j<EPB;j+=256){
    int e=base+j;
    int s=ei[e], d=ei[NEDGES+e];
    int p=atomicAdd(&offs[d>>8],1);
    ebuf[p]=make_int2(s,d);
  }
}

// ---------------- bucket sort pass D: per-bucket CSR (rp, dis, dinv, esrc) ----------------
__global__ __launch_bounds__(256) void k_bcsr(const int2* __restrict__ ebuf, const int* __restrict__ brow,
                                              int* __restrict__ rp, float* __restrict__ dis,
                                              float* __restrict__ dinv, int* __restrict__ esrc){
  __shared__ int lcnt[256], lrp[256], lfill[256];
  int b=blockIdx.x, t=threadIdx.x;
  int e0=brow[b], e1=brow[b+1];
  int n0=b*256, nloc=min(256, NNODES-n0);
  lcnt[t]=0;
  __syncthreads();
  for(int e=e0+t;e<e1;e+=256){
    int d=ebuf[e].y;
    atomicAdd(&lcnt[d&255],1);
  }
  __syncthreads();
  // inclusive scan of lcnt
  lrp[t]=lcnt[t]; __syncthreads();
  #pragma unroll
  for(int off=1;off<256;off<<=1){
    int u=(t>=off)?lrp[t-off]:0;
    __syncthreads();
    lrp[t]+=u;
    __syncthreads();
  }
  int excl=lrp[t]-lcnt[t];
  __syncthreads();
  lrp[t]=e0+excl;      // absolute segment base
  lfill[t]=0;
  if(t<nloc){
    int gid=n0+t;
    rp[gid]=e0+excl;
    float dd=(float)(lcnt[t]+1);
    dis[gid]=rsqrtf(dd);
    dinv[gid]=1.0f/dd;
  }
  __syncthreads();
  for(int e=e0+t;e<e1;e+=256){
    int2 r=ebuf[e];
    int lr=r.y&255;
    int slot=atomicAdd(&lfill[lr],1);
    esrc[lrp[lr]+slot]=r.x;
  }
}

// ---------------- generic 3-phase exclusive scan (kept for crow) ----------------
__global__ void k_scan1(const int* __restrict__ in, int n, int* __restrict__ part){
  int t=threadIdx.x, b=blockIdx.x;
  int base=b*1024+t*4, s=0;
  #pragma unroll
  for(int j=0;j<4;j++){ int i=base+j; if(i<n) s+=in[i]; }
  #pragma unroll
  for(int off=32;off>0;off>>=1) s+=__shfl_down(s,off,64);
  __shared__ int wm[4];
  if((t&63)==0) wm[t>>6]=s;
  __syncthreads();
  if(t==0) part[b]=wm[0]+wm[1]+wm[2]+wm[3];
}

__global__ void k_scan2(int* __restrict__ part, int P){
  __shared__ int sm[256];
  int t=threadIdx.x;
  int v=(t<P)?part[t]:0;
  sm[t]=v; __syncthreads();
  #pragma unroll
  for(int off=1;off<256;off<<=1){
    int u=(t>=off)?sm[t-off]:0;
    __syncthreads();
    sm[t]+=u;
    __syncthreads();
  }
  if(t<P) part[t]=(t==0)?0:sm[t-1];
  if(t==0) part[P]=sm[255];
}

__global__ void k_scan3(const int* __restrict__ in, int n, const int* __restrict__ part, int P,
                        int* __restrict__ out){
  int t=threadIdx.x,b=blockIdx.x;
  int base=b*1024+t*4;
  int v[4], ts=0;
  #pragma unroll
  for(int j=0;j<4;j++){ v[j]=(base+j<n)?in[base+j]:0; ts+=v[j]; }
  int lane=t&63, w=t>>6, sc=ts;
  #pragma unroll
  for(int off=1;off<64;off<<=1){ int u=__shfl_up(sc,off,64); if(lane>=off) sc+=u; }
  __shared__ int wm[4];
  if(lane==63) wm[w]=sc;
  __syncthreads();
  int woff=0;
  for(int i=0;i<w;i++) woff+=wm[i];
  int pos=part[b]+woff+sc-ts;
  #pragma unroll
  for(int j=0;j<4;j++){ if(base+j<n) out[base+j]=pos; pos+=v[j]; }
  if(b==0 && t==0) out[n]=part[P];
}

__global__ void k_fill_comm(const int* __restrict__ comm, const int* __restrict__ crow, int* __restrict__ cfill,
                            int* __restrict__ cnode){
  int i=blockIdx.x*blockDim.x+threadIdx.x;
  if(i<NNODES){
    int c=comm[i];
    int p=crow[c]+atomicAdd(&cfill[c],1);
    cnode[p]=i;
  }
}

// ---------------- community mean (f32) ----------------
__global__ void k_comm_mean(const float* __restrict__ x, const int* __restrict__ crow,
                            const int* __restrict__ cnode, float* __restrict__ cmean){
  int c=blockIdx.x; int f=threadIdx.x; // 128 threads
  int a=crow[c], b=crow[c+1];
  float s=0.f;
  for(int j=a;j<b;j++){
    int nd=cnode[j];
    s += x[(size_t)nd*INCH + f];
  }
  float cnt=(float)(b-a);
  cmean[(size_t)c*INCH + f] = s / fmaxf(cnt,1.0f);
}

// ---------------- weight prep: split f32 W[K][N] into transposed bf16 hi/lo planes [N][K] ----------------
__global__ void k_wprep(const float* __restrict__ W_in, const float* __restrict__ W1, const float* __restrict__ W2,
                        ushort16* __restrict__ Wt0h, ushort16* __restrict__ Wt0l,
                        ushort16* __restrict__ Wt1h, ushort16* __restrict__ Wt1l,
                        ushort16* __restrict__ Wt2h, ushort16* __restrict__ Wt2l){
  int t = blockIdx.x*256 + threadIdx.x;
  float v; ushort16* ph; ushort16* pl; int off;
  if(t < 32768){            // W_in: [256][128] -> Wt0[n=128][k=256]
    int n=t>>8, k=t&255; v=W_in[k*128+n]; ph=Wt0h; pl=Wt0l; off=t;
  } else if(t < 49152){     // W1: [128][128] -> Wt1[128][128]
    int u=t-32768; int n=u>>7, k=u&127; v=W1[k*128+n]; ph=Wt1h; pl=Wt1l; off=u;
  } else if(t < 55296){     // W2: [128][40] -> Wt2[48][128], rows 40..47 zero
    int u=t-49152; int n=u>>7, k=u&127; v=(n<40)?W2[k*40+n]:0.f; ph=Wt2h; pl=Wt2l; off=u;
  } else return;
  unsigned short h=f2b(v); unsigned short lo=f2b(v-b2f(h));
  ph[off]=h; pl[off]=lo;
}

// ---------------- MFMA GEMM: out[M][128](bf16) = A[M][K] @ W + (bias, relu) ----------------
template<int K, bool CONCAT, bool BIAS, bool RELU>
__global__ __launch_bounds__(256) void k_mm128(const void* __restrict__ A0, const float* __restrict__ A1f,
                                               const int* __restrict__ comm,
                                               const ushort16* __restrict__ WtH, const ushort16* __restrict__ WtL,
                                               const float* __restrict__ bias,
                                               ushort16* __restrict__ out, int M){
  __shared__ __align__(16) ushort16 As[128*40];   // row stride 40 ushorts (80B): 2-way bank alias only
  __shared__ __align__(16) ushort16 Bh[128*40];
  __shared__ __align__(16) ushort16 Bl[128*40];
  int t=threadIdx.x;
  int m0=blockIdx.x*128;
  int lane=t&63, w=t>>6;
  int g=lane>>4, r15=lane&15;

  f32x4 acc0[8], acc1[8];
  #pragma unroll
  for(int i=0;i<8;i++){ acc0[i]=(f32x4){0,0,0,0}; acc1[i]=(f32x4){0,0,0,0}; }

  int ar = t>>1, ko = (t&1)*16;     // staging coords: row, k-offset(16 elems)

  for(int kc=0;kc<K;kc+=32){
    __syncthreads();
    // ---- stage A chunk: 128 x 32 bf16 ----
    {
      s16x8 q0, q1;
      int gr = m0 + ar;
      if(gr < M){
        if(CONCAT){
          const float* src = (kc<128) ? ((const float*)A0 + (size_t)gr*128 + kc + ko)
                                      : (A1f + (size_t)comm[gr]*128 + (kc-128) + ko);
          float4 p0=ld4(src), p1=ld4(src+4), p2=ld4(src+8), p3=ld4(src+12);
          q0[0]=(short)f2b(p0.x); q0[1]=(short)f2b(p0.y); q0[2]=(short)f2b(p0.z); q0[3]=(short)f2b(p0.w);
          q0[4]=(short)f2b(p1.x); q0[5]=(short)f2b(p1.y); q0[6]=(short)f2b(p1.z); q0[7]=(short)f2b(p1.w);
          q1[0]=(short)f2b(p2.x); q1[1]=(short)f2b(p2.y); q1[2]=(short)f2b(p2.z); q1[3]=(short)f2b(p2.w);
          q1[4]=(short)f2b(p3.x); q1[5]=(short)f2b(p3.y); q1[6]=(short)f2b(p3.z); q1[7]=(short)f2b(p3.w);
        } else {
          const ushort16* srcu = (const ushort16*)A0 + (size_t)gr*K + kc + ko;
          q0 = *(const s16x8*)srcu;
          q1 = *(const s16x8*)(srcu+8);
        }
      } else {
        q0=(s16x8){0,0,0,0,0,0,0,0}; q1=q0;
      }
      ushort16* dst=&As[ar*40+ko];
      *(s16x8*)dst=q0; *(s16x8*)(dst+8)=q1;
    }
    // ---- stage B chunk: hi & lo planes ----
    {
      const ushort16* sh=&WtH[(size_t)ar*K + kc + ko];
      s16x8 b0=*(const s16x8*)sh, b1=*(const s16x8*)(sh+8);
      ushort16* dh=&Bh[ar*40+ko];
      *(s16x8*)dh=b0; *(s16x8*)(dh+8)=b1;
      const ushort16* sl=&WtL[(size_t)ar*K + kc + ko];
      s16x8 c0=*(const s16x8*)sl, c1=*(const s16x8*)(sl+8);
      ushort16* dl=&Bl[ar*40+ko];
      *(s16x8*)dl=c0; *(s16x8*)(dl+8)=c1;
    }
    __syncthreads();
    s16x8 a0 = *(const s16x8*)&As[(w*32      + r15)*40 + g*8];
    s16x8 a1 = *(const s16x8*)&As[(w*32 + 16 + r15)*40 + g*8];
    #pragma unroll
    for(int tn=0;tn<8;tn++){
      s16x8 bh = *(const s16x8*)&Bh[(tn*16 + r15)*40 + g*8];
      s16x8 bl = *(const s16x8*)&Bl[(tn*16 + r15)*40 + g*8];
      acc0[tn] = __builtin_amdgcn_mfma_f32_16x16x32_bf16(a0, bh, acc0[tn], 0,0,0);
      acc0[tn] = __builtin_amdgcn_mfma_f32_16x16x32_bf16(a0, bl, acc0[tn], 0,0,0);
      acc1[tn] = __builtin_amdgcn_mfma_f32_16x16x32_bf16(a1, bh, acc1[tn], 0,0,0);
      acc1[tn] = __builtin_amdgcn_mfma_f32_16x16x32_bf16(a1, bl, acc1[tn], 0,0,0);
    }
  }

  #pragma unroll
  for(int tn=0;tn<8;tn++){
    int col = tn*16 + r15;
    float bv = BIAS ? bias[col] : 0.f;
    #pragma unroll
    for(int rr=0;rr<4;rr++){
      int row0 = m0 + w*32 + g*4 + rr;
      if(row0 < M){
        float v = acc0[tn][rr] + bv;
        if(RELU) v = fmaxf(v, 0.f);
        out[(size_t)row0*128 + col] = f2b(v);
      }
      int row1 = m0 + w*32 + 16 + g*4 + rr;
      if(row1 < M){
        float v = acc1[tn][rr] + bv;
        if(RELU) v = fmaxf(v, 0.f);
        out[(size_t)row1*128 + col] = f2b(v);
      }
    }
  }
}

// ---------------- MFMA GEMM: hw2[M][40](bf16) = h1[M][128](bf16) @ W2 ----------------
__global__ __launch_bounds__(256) void k_mm40(const ushort16* __restrict__ A0,
                                              const ushort16* __restrict__ WtH, const ushort16* __restrict__ WtL,
                                              ushort16* __restrict__ out, int M){
  __shared__ __align__(16) ushort16 As[128*40];
  __shared__ __align__(16) ushort16 Bh[48*40];
  __shared__ __align__(16) ushort16 Bl[48*40];
  int t=threadIdx.x;
  int m0=blockIdx.x*128;
  int lane=t&63, w=t>>6;
  int g=lane>>4, r15=lane&15;

  f32x4 acc0[3], acc1[3];
  #pragma unroll
  for(int i=0;i<3;i++){ acc0[i]=(f32x4){0,0,0,0}; acc1[i]=(f32x4){0,0,0,0}; }

  int ar=t>>1, ko=(t&1)*16;

  for(int kc=0;kc<128;kc+=32){
    __syncthreads();
    {
      s16x8 q0,q1;
      int gr=m0+ar;
      if(gr<M){
        const ushort16* srcu = A0 + (size_t)gr*128 + kc + ko;
        q0=*(const s16x8*)srcu; q1=*(const s16x8*)(srcu+8);
      } else { q0=(s16x8){0,0,0,0,0,0,0,0}; q1=q0; }
      ushort16* dst=&As[ar*40+ko];
      *(s16x8*)dst=q0; *(s16x8*)(dst+8)=q1;
    }
    if(t<96){
      int n=t>>1, k2=(t&1)*16;
      const ushort16* sh=&WtH[(size_t)n*128 + kc + k2];
      s16x8 b0=*(const s16x8*)sh, b1=*(const s16x8*)(sh+8);
      ushort16* dh=&Bh[n*40+k2];
      *(s16x8*)dh=b0; *(s16x8*)(dh+8)=b1;
    } else if(t<192){
      int u=t-96; int n=u>>1, k2=(u&1)*16;
      const ushort16* sl=&WtL[(size_t)n*128 + kc + k2];
      s16x8 c0=*(const s16x8*)sl, c1=*(const s16x8*)(sl+8);
      ushort16* dl=&Bl[n*40+k2];
      *(s16x8*)dl=c0; *(s16x8*)(dl+8)=c1;
    }
    __syncthreads();
    s16x8 a0=*(const s16x8*)&As[(w*32      + r15)*40 + g*8];
    s16x8 a1=*(const s16x8*)&As[(w*32 + 16 + r15)*40 + g*8];
    #pragma unroll
    for(int tn=0;tn<3;tn++){
      s16x8 bh=*(const s16x8*)&Bh[(tn*16 + r15)*40 + g*8];
      s16x8 bl=*(const s16x8*)&Bl[(tn*16 + r15)*40 + g*8];
      acc0[tn]=__builtin_amdgcn_mfma_f32_16x16x32_bf16(a0,bh,acc0[tn],0,0,0);
      acc0[tn]=__builtin_amdgcn_mfma_f32_16x16x32_bf16(a0,bl,acc0[tn],0,0,0);
      acc1[tn]=__builtin_amdgcn_mfma_f32_16x16x32_bf16(a1,bh,acc1[tn],0,0,0);
      acc1[tn]=__builtin_amdgcn_mfma_f32_16x16x32_bf16(a1,bl,acc1[tn],0,0,0);
    }
  }
  #pragma unroll
  for(int tn=0;tn<3;tn++){
    int col=tn*16+r15;
    if(col<NCLS){
      #pragma unroll
      for(int rr=0;rr<4;rr++){
        int row0=m0+w*32+g*4+rr;
        if(row0<M) out[(size_t)row0*NCLS+col]=f2b(acc0[tn][rr]);
        int row1=m0+w*32+16+g*4+rr;
        if(row1<M) out[(size_t)row1*NCLS+col]=f2b(acc1[tn][rr]);
      }
    }
  }
}

// ---------------- aggregation layer1: 4 waves/block (1 node each); 4 edge-groups x 16 lanes ----------------
// lane f (0..15) covers feats [8f, 8f+7] via one uint4 (16B). Row = 16 uint4. 8 gathers in flight/wave.
__global__ __launch_bounds__(256) void k_agg_h(const uint4* __restrict__ hwv, const int* __restrict__ rp,
                                               const int* __restrict__ esrc,
                                               const float* __restrict__ dis, const float* __restrict__ dinv,
                                               const float* __restrict__ bias, uint4* __restrict__ h1v){
  int w=threadIdx.x>>6;
  int i=blockIdx.x*4+w;
  if(i>=NNODES) return;
  int lane=threadIdx.x&63;
  int g=lane>>4, f=lane&15;
  int e0=rp[i], e1=rp[i+1];
  float di=dis[i];
  float a[8]={0,0,0,0,0,0,0,0};
  int e=e0+g;
  for(; e+4<e1; e+=8){
    int s0=esrc[e], s1=esrc[e+4];
    float n0=di*dis[s0], n1=di*dis[s1];
    uint4 v0=hwv[(size_t)s0*16+f];
    uint4 v1=hwv[(size_t)s1*16+f];
    acc8(a,v0,n0); acc8(a,v1,n1);
  }
  if(e<e1){
    int s0=esrc[e];
    float n0=di*dis[s0];
    uint4 v0=hwv[(size_t)s0*16+f];
    acc8(a,v0,n0);
  }
  #pragma unroll
  for(int k=0;k<8;k++){
    a[k]+=__shfl_xor(a[k],16);
    a[k]+=__shfl_xor(a[k],32);
  }
  if(g==0){
    uint4 sv=hwv[(size_t)i*16+f];
    float dv=dinv[i];
    float4 bA=*reinterpret_cast<const float4*>(&bias[8*f]);
    float4 bB=*reinterpret_cast<const float4*>(&bias[8*f+4]);
    float o0=fmaxf(fmaf(lo16f(sv.x),dv,a[0])+bA.x,0.f);
    float o1=fmaxf(fmaf(hi16f(sv.x),dv,a[1])+bA.y,0.f);
    float o2=fmaxf(fmaf(lo16f(sv.y),dv,a[2])+bA.z,0.f);
    float o3=fmaxf(fmaf(hi16f(sv.y),dv,a[3])+bA.w,0.f);
    float o4=fmaxf(fmaf(lo16f(sv.z),dv,a[4])+bB.x,0.f);
    float o5=fmaxf(fmaf(hi16f(sv.z),dv,a[5])+bB.y,0.f);
    float o6=fmaxf(fmaf(lo16f(sv.w),dv,a[6])+bB.z,0.f);
    float o7=fmaxf(fmaf(hi16f(sv.w),dv,a[7])+bB.w,0.f);
    uint4 o;
    o.x=((uint32)f2b(o1)<<16)|(uint32)f2b(o0);
    o.y=((uint32)f2b(o3)<<16)|(uint32)f2b(o2);
    o.z=((uint32)f2b(o5)<<16)|(uint32)f2b(o4);
    o.w=((uint32)f2b(o7)<<16)|(uint32)f2b(o6);
    h1v[(size_t)i*16+f]=o;
  }
}

// ---------------- aggregation layer2: 4 waves/block; 4 edge-groups x 16 lanes (10 active) ----------------
__global__ __launch_bounds__(256) void k_agg_out(const uint2* __restrict__ hv, const int* __restrict__ rp,
                                                 const int* __restrict__ esrc,
                                                 const float* __restrict__ dis, const float* __restrict__ dinv,
                                                 const float* __restrict__ bias, float* __restrict__ out){
  int w=threadIdx.x>>6;
  int i=blockIdx.x*4+w;
  if(i>=NNODES) return;
  int lane=threadIdx.x&63;
  int g=lane>>4, f=lane&15;
  bool act=(f<10);
  int e0=rp[i], e1=rp[i+1];
  float di=dis[i];
  float a[4]={0,0,0,0};
  int e=e0+g;
  for(; e+4<e1; e+=8){
    int s0=esrc[e], s1=esrc[e+4];
    float n0=di*dis[s0], n1=di*dis[s1];
    if(act){
      uint2 v0=hv[(size_t)s0*10+f];
      uint2 v1=hv[(size_t)s1*10+f];
      acc4(a,v0,n0); acc4(a,v1,n1);
    }
  }
  if(e<e1){
    int s0=esrc[e];
    float n0=di*dis[s0];
    if(act){
      uint2 v0=hv[(size_t)s0*10+f];
      acc4(a,v0,n0);
    }
  }
  #pragma unroll
  for(int k=0;k<4;k++){
    a[k]+=__shfl_xor(a[k],16);
    a[k]+=__shfl_xor(a[k],32);
  }
  if(g==0 && act){
    uint2 sv=hv[(size_t)i*10+f];
    float dv=dinv[i];
    float4 b=*reinterpret_cast<const float4*>(&bias[4*f]);
    float4 o;
    o.x=fmaf(lo16f(sv.x),dv,a[0])+b.x;
    o.y=fmaf(hi16f(sv.x),dv,a[1])+b.y;
    o.z=fmaf(lo16f(sv.y),dv,a[2])+b.z;
    o.w=fmaf(hi16f(sv.y),dv,a[3])+b.w;
    *reinterpret_cast<float4*>(&out[(size_t)i*40+4*f])=o;
  }
}

// ---------------- launcher ----------------
extern "C" void kernel_launch(void* const* d_in, const int* in_sizes, int n_in,
                              void* d_out, int out_size, void* d_ws, size_t ws_size,
                              hipStream_t stream) {
  const float* x    = (const float*)d_in[0];
  const int*   ei   = (const int*)  d_in[1];
  const int*   comm = (const int*)  d_in[2];
  const float* W_in = (const float*)d_in[3];
  const float* b_in = (const float*)d_in[4];
  const float* W1   = (const float*)d_in[5];
  const float* b1   = (const float*)d_in[6];
  const float* W2   = (const float*)d_in[7];
  const float* b2   = (const float*)d_in[8];
  float* out = (float*)d_out;

  char* base=(char*)d_ws; size_t off=0;
  auto alloc=[&](size_t bytes)->void*{ void* p=base+off; off=(off+bytes+255)&~(size_t)255; return p; };

  // zero zone: ccnt, cfill
  int* zz    =(int*)alloc((size_t)(2*NCOMM_)*4);
  int* ccnt  = zz;
  int* cfill = zz + NCOMM_;
  int* cnt   =(int*)alloc((size_t)NCNT*4);
  int* brow  =(int*)alloc((size_t)(NBUCK+1)*4);
  int* rp    =(int*)alloc((size_t)(NNODES+1)*4);
  int* crow  =(int*)alloc((size_t)(NCOMM_+1)*4);
  int* partB =(int*)alloc(16*4);
  int2* ebuf =(int2*)alloc((size_t)NEDGES*8);
  int* esrc  =(int*)alloc((size_t)NEDGES*4);
  int* cnode =(int*)alloc((size_t)NNODES*4);
  float* dis =(float*)alloc((size_t)NNODES*4);
  float* dinv=(float*)alloc((size_t)NNODES*4);
  float* cmean=(float*)alloc((size_t)NCOMM_*INCH*4);
  ushort16* h0 =(ushort16*)alloc((size_t)NNODES*HID*2);   // bf16; reused as h1
  ushort16* hw =(ushort16*)alloc((size_t)NNODES*HID*2);   // bf16; reused as hw2
  ushort16* Wt0h=(ushort16*)alloc(32768*2);
  ushort16* Wt0l=(ushort16*)alloc(32768*2);
  ushort16* Wt1h=(ushort16*)alloc(16384*2);
  ushort16* Wt1l=(ushort16*)alloc(16384*2);
  ushort16* Wt2h=(ushort16*)alloc(6144*2);
  ushort16* Wt2l=(ushort16*)alloc(6144*2);

  hipMemsetAsync(zz, 0, (size_t)(2*NCOMM_)*4, stream);

  int gN=(NNODES+255)/256;

  // ---- CSR build via deterministic bucket sort (no global atomics) ----
  k_bcnt    <<<NBLK,256,0,stream>>>(ei, cnt);
  k_bscan   <<<1,1024,0,stream>>>(cnt, brow, rp);
  k_bscatter<<<NBLK,256,0,stream>>>(ei, cnt, ebuf);
  k_bcsr    <<<NBUCK,256,0,stream>>>(ebuf, brow, rp, dis, dinv, esrc);

  // ---- community CSR (small; atomics fine) ----
  k_ccomm<<<gN,256,0,stream>>>(comm, ccnt);
  int PB=(NCOMM_+1023)/1024;   // 1
  k_scan1<<<PB,256,0,stream>>>(ccnt, NCOMM_, partB);
  k_scan2<<<1,256,0,stream>>>(partB, PB);
  k_scan3<<<PB,256,0,stream>>>(ccnt, NCOMM_, partB, PB, crow);
  k_fill_comm<<<gN,256,0,stream>>>(comm, crow, cfill, cnode);
  k_comm_mean<<<NCOMM_,128,0,stream>>>(x, crow, cnode, cmean);
  k_wprep<<<216,256,0,stream>>>(W_in, W1, W2, Wt0h, Wt0l, Wt1h, Wt1l, Wt2h, Wt2l);

  int gM=(NNODES+127)/128;
  // h0 = relu([x | cmean[comm]] @ W_in + b_in)   (bf16 out)
  k_mm128<256,true,true,true><<<gM,256,0,stream>>>(x, cmean, comm, Wt0h, Wt0l, b_in, h0, NNODES);
  // hw = h0 @ W1  (bf16 out)
  k_mm128<128,false,false,false><<<gM,256,0,stream>>>(h0, nullptr, nullptr, Wt1h, Wt1l, nullptr, hw, NNODES);
  // h1 (into h0 buffer) = relu(agg(hw) + hw*dinv + b1)
  int gA=(NNODES+3)/4;
  k_agg_h<<<gA,256,0,stream>>>((const uint4*)hw, rp, esrc, dis, dinv, b1, (uint4*)h0);
  // hw2 (into hw buffer) = h1 @ W2
  k_mm40<<<gM,256,0,stream>>>(h0, Wt2h, Wt2l, hw, NNODES);
  // out = agg(hw2) + hw2*dinv + b2
  k_agg_out<<<gA,256,0,stream>>>((const uint2*)hw, rp, esrc, dis, dinv, b2, out);
}

// Round 7
// 472.718 us; speedup vs baseline: 1.1688x; 1.1688x over previous
//
#include <hip/hip_runtime.h>
#include <cstdint>
#include <cstddef>

#define NNODES 100000
#define NEDGES 1600000
#define INCH   128
#define HID    128
#define NCLS   40
#define NCOMM_ 1000

#define NBLK  128                 // partition blocks for bucket sort
#define EPB   (NEDGES/NBLK)       // 12500 edges per block (exact)
#define NBUCK ((NNODES+255)/256)  // 391 buckets of 256 nodes
#define NCNT  (NBLK*NBUCK)

typedef unsigned int uint32;
typedef unsigned short ushort16;
typedef short s16x8 __attribute__((ext_vector_type(8)));
typedef float f32x4 __attribute__((ext_vector_type(4)));

static __device__ __forceinline__ float4 ld4(const float* p){ return *reinterpret_cast<const float4*>(p); }

// f32 -> bf16 (RTN-even) and back, via bit ops
static __device__ __forceinline__ unsigned short f2b(float f){
  union{float f; uint32 u;} v; v.f=f;
  uint32 r = v.u + 0x7fffu + ((v.u>>16)&1u);
  return (unsigned short)(r>>16);
}
static __device__ __forceinline__ float b2f(unsigned short h){
  union{uint32 u; float f;} v; v.u = ((uint32)h)<<16; return v.f;
}
static __device__ __forceinline__ float lo16f(uint32 u){ return __int_as_float((int)(u<<16)); }
static __device__ __forceinline__ float hi16f(uint32 u){ return __int_as_float((int)(u&0xffff0000u)); }

static __device__ __forceinline__ void acc8(float* a, uint4 v, float nr){
  a[0]=fmaf(lo16f(v.x),nr,a[0]); a[1]=fmaf(hi16f(v.x),nr,a[1]);
  a[2]=fmaf(lo16f(v.y),nr,a[2]); a[3]=fmaf(hi16f(v.y),nr,a[3]);
  a[4]=fmaf(lo16f(v.z),nr,a[4]); a[5]=fmaf(hi16f(v.z),nr,a[5]);
  a[6]=fmaf(lo16f(v.w),nr,a[6]); a[7]=fmaf(hi16f(v.w),nr,a[7]);
}
static __device__ __forceinline__ void acc4(float* a, uint2 v, float nr){
  a[0]=fmaf(lo16f(v.x),nr,a[0]); a[1]=fmaf(hi16f(v.x),nr,a[1]);
  a[2]=fmaf(lo16f(v.y),nr,a[2]); a[3]=fmaf(hi16f(v.y),nr,a[3]);
}

// ---------------- community counting (atomics; only 100K over 1000 bins) ----------------
__global__ void k_ccomm(const int* __restrict__ comm, int* __restrict__ ccnt){
  int i=blockIdx.x*blockDim.x+threadIdx.x;
  if(i<NNODES) atomicAdd(&ccnt[comm[i]],1);
}

// ---------------- bucket sort pass A: per-block LDS histogram over dst>>8 ----------------
__global__ __launch_bounds__(256) void k_bcnt(const int* __restrict__ ei, int* __restrict__ cnt){
  __shared__ int h[NBUCK];
  int t=threadIdx.x, blk=blockIdx.x;
  for(int i=t;i<NBUCK;i+=256) h[i]=0;
  __syncthreads();
  int base=blk*EPB;
  for(int j=t;j<EPB;j+=256){
    int d=ei[NEDGES+base+j];
    atomicAdd(&h[d>>8],1);
  }
  __syncthreads();
  for(int i=t;i<NBUCK;i+=256) cnt[i*NBLK+blk]=h[i];
}

// ---------------- generic 3-phase exclusive scan ----------------
__global__ void k_scan1(const int* __restrict__ in, int n, int* __restrict__ part){
  int t=threadIdx.x, b=blockIdx.x;
  int base=b*1024+t*4, s=0;
  #pragma unroll
  for(int j=0;j<4;j++){ int i=base+j; if(i<n) s+=in[i]; }
  #pragma unroll
  for(int off=32;off>0;off>>=1) s+=__shfl_down(s,off,64);
  __shared__ int wm[4];
  if((t&63)==0) wm[t>>6]=s;
  __syncthreads();
  if(t==0) part[b]=wm[0]+wm[1]+wm[2]+wm[3];
}

__global__ void k_scan2(int* __restrict__ part, int P){
  __shared__ int sm[256];
  int t=threadIdx.x;
  int v=(t<P)?part[t]:0;
  sm[t]=v; __syncthreads();
  #pragma unroll
  for(int off=1;off<256;off<<=1){
    int u=(t>=off)?sm[t-off]:0;
    __syncthreads();
    sm[t]+=u;
    __syncthreads();
  }
  if(t<P) part[t]=(t==0)?0:sm[t-1];
  if(t==0) part[P]=sm[255];
}

__global__ void k_scan3(const int* __restrict__ in, int n, const int* __restrict__ part, int P,
                        int* __restrict__ out){
  int t=threadIdx.x,b=blockIdx.x;
  int base=b*1024+t*4;
  int v[4], ts=0;
  #pragma unroll
  for(int j=0;j<4;j++){ v[j]=(base+j<n)?in[base+j]:0; ts+=v[j]; }
  int lane=t&63, w=t>>6, sc=ts;
  #pragma unroll
  for(int off=1;off<64;off<<=1){ int u=__shfl_up(sc,off,64); if(lane>=off) sc+=u; }
  __shared__ int wm[4];
  if(lane==63) wm[w]=sc;
  __syncthreads();
  int woff=0;
  for(int i=0;i<w;i++) woff+=wm[i];
  int pos=part[b]+woff+sc-ts;
  #pragma unroll
  for(int j=0;j<4;j++){ if(base+j<n) out[base+j]=pos; pos+=v[j]; }
  if(b==0 && t==0) out[n]=part[P];
}

// ---------------- extract bucket bases from scanned cnt ----------------
__global__ void k_bextract(const int* __restrict__ cntx, int* __restrict__ brow, int* __restrict__ rp){
  int b=blockIdx.x*blockDim.x+threadIdx.x;
  if(b<NBUCK) brow[b]=cntx[b*NBLK];
  if(b==NBUCK){ brow[NBUCK]=NEDGES; rp[NNODES]=NEDGES; }
}

// ---------------- bucket sort pass C: deterministic scatter into bucket-partitioned ebuf ----------------
__global__ __launch_bounds__(256) void k_bscatter(const int* __restrict__ ei, const int* __restrict__ cntx,
                                                  int2* __restrict__ ebuf){
  __shared__ int offs[NBUCK];
  int t=threadIdx.x, blk=blockIdx.x;
  for(int i=t;i<NBUCK;i+=256) offs[i]=cntx[i*NBLK+blk];
  __syncthreads();
  int base=blk*EPB;
  for(int j=t;j<EPB;j+=256){
    int e=base+j;
    int s=ei[e], d=ei[NEDGES+e];
    int p=atomicAdd(&offs[d>>8],1);
    ebuf[p]=make_int2(s,d);
  }
}

// ---------------- bucket sort pass D: per-bucket CSR (rp, dis, dinv, esrc) ----------------
__global__ __launch_bounds__(256) void k_bcsr(const int2* __restrict__ ebuf, const int* __restrict__ brow,
                                              int* __restrict__ rp, float* __restrict__ dis,
                                              float* __restrict__ dinv, int* __restrict__ esrc){
  __shared__ int lcnt[256], lrp[256], lfill[256];
  int b=blockIdx.x, t=threadIdx.x;
  int e0=brow[b], e1=brow[b+1];
  int n0=b*256, nloc=min(256, NNODES-n0);
  lcnt[t]=0;
  __syncthreads();
  for(int e=e0+t;e<e1;e+=256){
    int d=ebuf[e].y;
    atomicAdd(&lcnt[d&255],1);
  }
  __syncthreads();
  // inclusive scan of lcnt
  lrp[t]=lcnt[t]; __syncthreads();
  #pragma unroll
  for(int off=1;off<256;off<<=1){
    int u=(t>=off)?lrp[t-off]:0;
    __syncthreads();
    lrp[t]+=u;
    __syncthreads();
  }
  int excl=lrp[t]-lcnt[t];
  __syncthreads();
  lrp[t]=e0+excl;      // absolute segment base
  lfill[t]=0;
  if(t<nloc){
    int gid=n0+t;
    rp[gid]=e0+excl;
    float dd=(float)(lcnt[t]+1);
    dis[gid]=rsqrtf(dd);
    dinv[gid]=1.0f/dd;
  }
  __syncthreads();
  for(int e=e0+t;e<e1;e+=256){
    int2 r=ebuf[e];
    int lr=r.y&255;
    int slot=atomicAdd(&lfill[lr],1);
    esrc[lrp[lr]+slot]=r.x;
  }
}

__global__ void k_fill_comm(const int* __restrict__ comm, const int* __restrict__ crow, int* __restrict__ cfill,
                            int* __restrict__ cnode){
  int i=blockIdx.x*blockDim.x+threadIdx.x;
  if(i<NNODES){
    int c=comm[i];
    int p=crow[c]+atomicAdd(&cfill[c],1);
    cnode[p]=i;
  }
}

// ---------------- community mean (f32) ----------------
__global__ void k_comm_mean(const float* __restrict__ x, const int* __restrict__ crow,
                            const int* __restrict__ cnode, float* __restrict__ cmean){
  int c=blockIdx.x; int f=threadIdx.x; // 128 threads
  int a=crow[c], b=crow[c+1];
  float s=0.f;
  for(int j=a;j<b;j++){
    int nd=cnode[j];
    s += x[(size_t)nd*INCH + f];
  }
  float cnt=(float)(b-a);
  cmean[(size_t)c*INCH + f] = s / fmaxf(cnt,1.0f);
}

// ---------------- weight prep: split f32 W[K][N] into transposed bf16 hi/lo planes [N][K] ----------------
__global__ void k_wprep(const float* __restrict__ W_in, const float* __restrict__ W1, const float* __restrict__ W2,
                        ushort16* __restrict__ Wt0h, ushort16* __restrict__ Wt0l,
                        ushort16* __restrict__ Wt1h, ushort16* __restrict__ Wt1l,
                        ushort16* __restrict__ Wt2h, ushort16* __restrict__ Wt2l){
  int t = blockIdx.x*256 + threadIdx.x;
  float v; ushort16* ph; ushort16* pl; int off;
  if(t < 32768){            // W_in: [256][128] -> Wt0[n=128][k=256]
    int n=t>>8, k=t&255; v=W_in[k*128+n]; ph=Wt0h; pl=Wt0l; off=t;
  } else if(t < 49152){     // W1: [128][128] -> Wt1[128][128]
    int u=t-32768; int n=u>>7, k=u&127; v=W1[k*128+n]; ph=Wt1h; pl=Wt1l; off=u;
  } else if(t < 55296){     // W2: [128][40] -> Wt2[48][128], rows 40..47 zero
    int u=t-49152; int n=u>>7, k=u&127; v=(n<40)?W2[k*40+n]:0.f; ph=Wt2h; pl=Wt2l; off=u;
  } else return;
  unsigned short h=f2b(v); unsigned short lo=f2b(v-b2f(h));
  ph[off]=h; pl[off]=lo;
}

// ---------------- MFMA GEMM: out[M][128](bf16) = A[M][K] @ W + (bias, relu) ----------------
template<int K, bool CONCAT, bool BIAS, bool RELU>
__global__ __launch_bounds__(256) void k_mm128(const void* __restrict__ A0, const float* __restrict__ A1f,
                                               const int* __restrict__ comm,
                                               const ushort16* __restrict__ WtH, const ushort16* __restrict__ WtL,
                                               const float* __restrict__ bias,
                                               ushort16* __restrict__ out, int M){
  __shared__ __align__(16) ushort16 As[128*40];   // row stride 40 ushorts (80B): 2-way bank alias only
  __shared__ __align__(16) ushort16 Bh[128*40];
  __shared__ __align__(16) ushort16 Bl[128*40];
  int t=threadIdx.x;
  int m0=blockIdx.x*128;
  int lane=t&63, w=t>>6;
  int g=lane>>4, r15=lane&15;

  f32x4 acc0[8], acc1[8];
  #pragma unroll
  for(int i=0;i<8;i++){ acc0[i]=(f32x4){0,0,0,0}; acc1[i]=(f32x4){0,0,0,0}; }

  int ar = t>>1, ko = (t&1)*16;     // staging coords: row, k-offset(16 elems)

  for(int kc=0;kc<K;kc+=32){
    __syncthreads();
    // ---- stage A chunk: 128 x 32 bf16 ----
    {
      s16x8 q0, q1;
      int gr = m0 + ar;
      if(gr < M){
        if(CONCAT){
          const float* src = (kc<128) ? ((const float*)A0 + (size_t)gr*128 + kc + ko)
                                      : (A1f + (size_t)comm[gr]*128 + (kc-128) + ko);
          float4 p0=ld4(src), p1=ld4(src+4), p2=ld4(src+8), p3=ld4(src+12);
          q0[0]=(short)f2b(p0.x); q0[1]=(short)f2b(p0.y); q0[2]=(short)f2b(p0.z); q0[3]=(short)f2b(p0.w);
          q0[4]=(short)f2b(p1.x); q0[5]=(short)f2b(p1.y); q0[6]=(short)f2b(p1.z); q0[7]=(short)f2b(p1.w);
          q1[0]=(short)f2b(p2.x); q1[1]=(short)f2b(p2.y); q1[2]=(short)f2b(p2.z); q1[3]=(short)f2b(p2.w);
          q1[4]=(short)f2b(p3.x); q1[5]=(short)f2b(p3.y); q1[6]=(short)f2b(p3.z); q1[7]=(short)f2b(p3.w);
        } else {
          const ushort16* srcu = (const ushort16*)A0 + (size_t)gr*K + kc + ko;
          q0 = *(const s16x8*)srcu;
          q1 = *(const s16x8*)(srcu+8);
        }
      } else {
        q0=(s16x8){0,0,0,0,0,0,0,0}; q1=q0;
      }
      ushort16* dst=&As[ar*40+ko];
      *(s16x8*)dst=q0; *(s16x8*)(dst+8)=q1;
    }
    // ---- stage B chunk: hi & lo planes ----
    {
      const ushort16* sh=&WtH[(size_t)ar*K + kc + ko];
      s16x8 b0=*(const s16x8*)sh, b1=*(const s16x8*)(sh+8);
      ushort16* dh=&Bh[ar*40+ko];
      *(s16x8*)dh=b0; *(s16x8*)(dh+8)=b1;
      const ushort16* sl=&WtL[(size_t)ar*K + kc + ko];
      s16x8 c0=*(const s16x8*)sl, c1=*(const s16x8*)(sl+8);
      ushort16* dl=&Bl[ar*40+ko];
      *(s16x8*)dl=c0; *(s16x8*)(dl+8)=c1;
    }
    __syncthreads();
    s16x8 a0 = *(const s16x8*)&As[(w*32      + r15)*40 + g*8];
    s16x8 a1 = *(const s16x8*)&As[(w*32 + 16 + r15)*40 + g*8];
    #pragma unroll
    for(int tn=0;tn<8;tn++){
      s16x8 bh = *(const s16x8*)&Bh[(tn*16 + r15)*40 + g*8];
      s16x8 bl = *(const s16x8*)&Bl[(tn*16 + r15)*40 + g*8];
      acc0[tn] = __builtin_amdgcn_mfma_f32_16x16x32_bf16(a0, bh, acc0[tn], 0,0,0);
      acc0[tn] = __builtin_amdgcn_mfma_f32_16x16x32_bf16(a0, bl, acc0[tn], 0,0,0);
      acc1[tn] = __builtin_amdgcn_mfma_f32_16x16x32_bf16(a1, bh, acc1[tn], 0,0,0);
      acc1[tn] = __builtin_amdgcn_mfma_f32_16x16x32_bf16(a1, bl, acc1[tn], 0,0,0);
    }
  }

  #pragma unroll
  for(int tn=0;tn<8;tn++){
    int col = tn*16 + r15;
    float bv = BIAS ? bias[col] : 0.f;
    #pragma unroll
    for(int rr=0;rr<4;rr++){
      int row0 = m0 + w*32 + g*4 + rr;
      if(row0 < M){
        float v = acc0[tn][rr] + bv;
        if(RELU) v = fmaxf(v, 0.f);
        out[(size_t)row0*128 + col] = f2b(v);
      }
      int row1 = m0 + w*32 + 16 + g*4 + rr;
      if(row1 < M){
        float v = acc1[tn][rr] + bv;
        if(RELU) v = fmaxf(v, 0.f);
        out[(size_t)row1*128 + col] = f2b(v);
      }
    }
  }
}

// ---------------- MFMA GEMM: hw2[M][40](bf16) = h1[M][128](bf16) @ W2 ----------------
__global__ __launch_bounds__(256) void k_mm40(const ushort16* __restrict__ A0,
                                              const ushort16* __restrict__ WtH, const ushort16* __restrict__ WtL,
                                              ushort16* __restrict__ out, int M){
  __shared__ __align__(16) ushort16 As[128*40];
  __shared__ __align__(16) ushort16 Bh[48*40];
  __shared__ __align__(16) ushort16 Bl[48*40];
  int t=threadIdx.x;
  int m0=blockIdx.x*128;
  int lane=t&63, w=t>>6;
  int g=lane>>4, r15=lane&15;

  f32x4 acc0[3], acc1[3];
  #pragma unroll
  for(int i=0;i<3;i++){ acc0[i]=(f32x4){0,0,0,0}; acc1[i]=(f32x4){0,0,0,0}; }

  int ar=t>>1, ko=(t&1)*16;

  for(int kc=0;kc<128;kc+=32){
    __syncthreads();
    {
      s16x8 q0,q1;
      int gr=m0+ar;
      if(gr<M){
        const ushort16* srcu = A0 + (size_t)gr*128 + kc + ko;
        q0=*(const s16x8*)srcu; q1=*(const s16x8*)(srcu+8);
      } else { q0=(s16x8){0,0,0,0,0,0,0,0}; q1=q0; }
      ushort16* dst=&As[ar*40+ko];
      *(s16x8*)dst=q0; *(s16x8*)(dst+8)=q1;
    }
    if(t<96){
      int n=t>>1, k2=(t&1)*16;
      const ushort16* sh=&WtH[(size_t)n*128 + kc + k2];
      s16x8 b0=*(const s16x8*)sh, b1=*(const s16x8*)(sh+8);
      ushort16* dh=&Bh[n*40+k2];
      *(s16x8*)dh=b0; *(s16x8*)(dh+8)=b1;
    } else if(t<192){
      int u=t-96; int n=u>>1, k2=(u&1)*16;
      const ushort16* sl=&WtL[(size_t)n*128 + kc + k2];
      s16x8 c0=*(const s16x8*)sl, c1=*(const s16x8*)(sl+8);
      ushort16* dl=&Bl[n*40+k2];
      *(s16x8*)dl=c0; *(s16x8*)(dl+8)=c1;
    }
    __syncthreads();
    s16x8 a0=*(const s16x8*)&As[(w*32      + r15)*40 + g*8];
    s16x8 a1=*(const s16x8*)&As[(w*32 + 16 + r15)*40 + g*8];
    #pragma unroll
    for(int tn=0;tn<3;tn++){
      s16x8 bh=*(const s16x8*)&Bh[(tn*16 + r15)*40 + g*8];
      s16x8 bl=*(const s16x8*)&Bl[(tn*16 + r15)*40 + g*8];
      acc0[tn]=__builtin_amdgcn_mfma_f32_16x16x32_bf16(a0,bh,acc0[tn],0,0,0);
      acc0[tn]=__builtin_amdgcn_mfma_f32_16x16x32_bf16(a0,bl,acc0[tn],0,0,0);
      acc1[tn]=__builtin_amdgcn_mfma_f32_16x16x32_bf16(a1,bh,acc1[tn],0,0,0);
      acc1[tn]=__builtin_amdgcn_mfma_f32_16x16x32_bf16(a1,bl,acc1[tn],0,0,0);
    }
  }
  #pragma unroll
  for(int tn=0;tn<3;tn++){
    int col=tn*16+r15;
    if(col<NCLS){
      #pragma unroll
      for(int rr=0;rr<4;rr++){
        int row0=m0+w*32+g*4+rr;
        if(row0<M) out[(size_t)row0*NCLS+col]=f2b(acc0[tn][rr]);
        int row1=m0+w*32+16+g*4+rr;
        if(row1<M) out[(size_t)row1*NCLS+col]=f2b(acc1[tn][rr]);
      }
    }
  }
}

// ---------------- aggregation layer1: 4 waves/block (1 node each); 4 edge-groups x 16 lanes ----------------
__global__ __launch_bounds__(256) void k_agg_h(const uint4* __restrict__ hwv, const int* __restrict__ rp,
                                               const int* __restrict__ esrc,
                                               const float* __restrict__ dis, const float* __restrict__ dinv,
                                               const float* __restrict__ bias, uint4* __restrict__ h1v){
  int w=threadIdx.x>>6;
  int i=blockIdx.x*4+w;
  if(i>=NNODES) return;
  int lane=threadIdx.x&63;
  int g=lane>>4, f=lane&15;
  int e0=rp[i], e1=rp[i+1];
  float di=dis[i];
  float a[8]={0,0,0,0,0,0,0,0};
  int e=e0+g;
  for(; e+4<e1; e+=8){
    int s0=esrc[e], s1=esrc[e+4];
    float n0=di*dis[s0], n1=di*dis[s1];
    uint4 v0=hwv[(size_t)s0*16+f];
    uint4 v1=hwv[(size_t)s1*16+f];
    acc8(a,v0,n0); acc8(a,v1,n1);
  }
  if(e<e1){
    int s0=esrc[e];
    float n0=di*dis[s0];
    uint4 v0=hwv[(size_t)s0*16+f];
    acc8(a,v0,n0);
  }
  #pragma unroll
  for(int k=0;k<8;k++){
    a[k]+=__shfl_xor(a[k],16);
    a[k]+=__shfl_xor(a[k],32);
  }
  if(g==0){
    uint4 sv=hwv[(size_t)i*16+f];
    float dv=dinv[i];
    float4 bA=*reinterpret_cast<const float4*>(&bias[8*f]);
    float4 bB=*reinterpret_cast<const float4*>(&bias[8*f+4]);
    float o0=fmaxf(fmaf(lo16f(sv.x),dv,a[0])+bA.x,0.f);
    float o1=fmaxf(fmaf(hi16f(sv.x),dv,a[1])+bA.y,0.f);
    float o2=fmaxf(fmaf(lo16f(sv.y),dv,a[2])+bA.z,0.f);
    float o3=fmaxf(fmaf(hi16f(sv.y),dv,a[3])+bA.w,0.f);
    float o4=fmaxf(fmaf(lo16f(sv.z),dv,a[4])+bB.x,0.f);
    float o5=fmaxf(fmaf(hi16f(sv.z),dv,a[5])+bB.y,0.f);
    float o6=fmaxf(fmaf(lo16f(sv.w),dv,a[6])+bB.z,0.f);
    float o7=fmaxf(fmaf(hi16f(sv.w),dv,a[7])+bB.w,0.f);
    uint4 o;
    o.x=((uint32)f2b(o1)<<16)|(uint32)f2b(o0);
    o.y=((uint32)f2b(o3)<<16)|(uint32)f2b(o2);
    o.z=((uint32)f2b(o5)<<16)|(uint32)f2b(o4);
    o.w=((uint32)f2b(o7)<<16)|(uint32)f2b(o6);
    h1v[(size_t)i*16+f]=o;
  }
}

// ---------------- aggregation layer2: 4 waves/block; 4 edge-groups x 16 lanes (10 active) ----------------
__global__ __launch_bounds__(256) void k_agg_out(const uint2* __restrict__ hv, const int* __restrict__ rp,
                                                 const int* __restrict__ esrc,
                                                 const float* __restrict__ dis, const float* __restrict__ dinv,
                                                 const float* __restrict__ bias, float* __restrict__ out){
  int w=threadIdx.x>>6;
  int i=blockIdx.x*4+w;
  if(i>=NNODES) return;
  int lane=threadIdx.x&63;
  int g=lane>>4, f=lane&15;
  bool act=(f<10);
  int e0=rp[i], e1=rp[i+1];
  float di=dis[i];
  float a[4]={0,0,0,0};
  int e=e0+g;
  for(; e+4<e1; e+=8){
    int s0=esrc[e], s1=esrc[e+4];
    float n0=di*dis[s0], n1=di*dis[s1];
    if(act){
      uint2 v0=hv[(size_t)s0*10+f];
      uint2 v1=hv[(size_t)s1*10+f];
      acc4(a,v0,n0); acc4(a,v1,n1);
    }
  }
  if(e<e1){
    int s0=esrc[e];
    float n0=di*dis[s0];
    if(act){
      uint2 v0=hv[(size_t)s0*10+f];
      acc4(a,v0,n0);
    }
  }
  #pragma unroll
  for(int k=0;k<4;k++){
    a[k]+=__shfl_xor(a[k],16);
    a[k]+=__shfl_xor(a[k],32);
  }
  if(g==0 && act){
    uint2 sv=hv[(size_t)i*10+f];
    float dv=dinv[i];
    float4 b=*reinterpret_cast<const float4*>(&bias[4*f]);
    float4 o;
    o.x=fmaf(lo16f(sv.x),dv,a[0])+b.x;
    o.y=fmaf(hi16f(sv.x),dv,a[1])+b.y;
    o.z=fmaf(lo16f(sv.y),dv,a[2])+b.z;
    o.w=fmaf(hi16f(sv.y),dv,a[3])+b.w;
    *reinterpret_cast<float4*>(&out[(size_t)i*40+4*f])=o;
  }
}

// ---------------- launcher ----------------
extern "C" void kernel_launch(void* const* d_in, const int* in_sizes, int n_in,
                              void* d_out, int out_size, void* d_ws, size_t ws_size,
                              hipStream_t stream) {
  const float* x    = (const float*)d_in[0];
  const int*   ei   = (const int*)  d_in[1];
  const int*   comm = (const int*)  d_in[2];
  const float* W_in = (const float*)d_in[3];
  const float* b_in = (const float*)d_in[4];
  const float* W1   = (const float*)d_in[5];
  const float* b1   = (const float*)d_in[6];
  const float* W2   = (const float*)d_in[7];
  const float* b2   = (const float*)d_in[8];
  float* out = (float*)d_out;

  char* base=(char*)d_ws; size_t off=0;
  auto alloc=[&](size_t bytes)->void*{ void* p=base+off; off=(off+bytes+255)&~(size_t)255; return p; };

  // zero zone: ccnt, cfill
  int* zz    =(int*)alloc((size_t)(2*NCOMM_)*4);
  int* ccnt  = zz;
  int* cfill = zz + NCOMM_;
  int* cnt   =(int*)alloc((size_t)NCNT*4);
  int* cntx  =(int*)alloc((size_t)(NCNT+1)*4);
  int* partA =(int*)alloc(64*4);
  int* brow  =(int*)alloc((size_t)(NBUCK+1)*4);
  int* rp    =(int*)alloc((size_t)(NNODES+1)*4);
  int* crow  =(int*)alloc((size_t)(NCOMM_+1)*4);
  int* partB =(int*)alloc(16*4);
  int2* ebuf =(int2*)alloc((size_t)NEDGES*8);
  int* esrc  =(int*)alloc((size_t)NEDGES*4);
  int* cnode =(int*)alloc((size_t)NNODES*4);
  float* dis =(float*)alloc((size_t)NNODES*4);
  float* dinv=(float*)alloc((size_t)NNODES*4);
  float* cmean=(float*)alloc((size_t)NCOMM_*INCH*4);
  ushort16* h0 =(ushort16*)alloc((size_t)NNODES*HID*2);   // bf16; reused as h1
  ushort16* hw =(ushort16*)alloc((size_t)NNODES*HID*2);   // bf16; reused as hw2
  ushort16* Wt0h=(ushort16*)alloc(32768*2);
  ushort16* Wt0l=(ushort16*)alloc(32768*2);
  ushort16* Wt1h=(ushort16*)alloc(16384*2);
  ushort16* Wt1l=(ushort16*)alloc(16384*2);
  ushort16* Wt2h=(ushort16*)alloc(6144*2);
  ushort16* Wt2l=(ushort16*)alloc(6144*2);

  hipMemsetAsync(zz, 0, (size_t)(2*NCOMM_)*4, stream);

  int gN=(NNODES+255)/256;

  // ---- CSR build via deterministic bucket sort (no global atomics) ----
  k_bcnt    <<<NBLK,256,0,stream>>>(ei, cnt);
  int PC=(NCNT+1023)/1024;   // 49 blocks
  k_scan1<<<PC,256,0,stream>>>(cnt, NCNT, partA);
  k_scan2<<<1,256,0,stream>>>(partA, PC);
  k_scan3<<<PC,256,0,stream>>>(cnt, NCNT, partA, PC, cntx);
  k_bextract<<<(NBUCK+256)/256,256,0,stream>>>(cntx, brow, rp);
  k_bscatter<<<NBLK,256,0,stream>>>(ei, cntx, ebuf);
  k_bcsr    <<<NBUCK,256,0,stream>>>(ebuf, brow, rp, dis, dinv, esrc);

  // ---- community CSR (small; atomics fine) ----
  k_ccomm<<<gN,256,0,stream>>>(comm, ccnt);
  int PB=(NCOMM_+1023)/1024;   // 1
  k_scan1<<<PB,256,0,stream>>>(ccnt, NCOMM_, partB);
  k_scan2<<<1,256,0,stream>>>(partB, PB);
  k_scan3<<<PB,256,0,stream>>>(ccnt, NCOMM_, partB, PB, crow);
  k_fill_comm<<<gN,256,0,stream>>>(comm, crow, cfill, cnode);
  k_comm_mean<<<NCOMM_,128,0,stream>>>(x, crow, cnode, cmean);
  k_wprep<<<216,256,0,stream>>>(W_in, W1, W2, Wt0h, Wt0l, Wt1h, Wt1l, Wt2h, Wt2l);

  int gM=(NNODES+127)/128;
  // h0 = relu([x | cmean[comm]] @ W_in + b_in)   (bf16 out)
  k_mm128<256,true,true,true><<<gM,256,0,stream>>>(x, cmean, comm, Wt0h, Wt0l, b_in, h0, NNODES);
  // hw = h0 @ W1  (bf16 out)
  k_mm128<128,false,false,false><<<gM,256,0,stream>>>(h0, nullptr, nullptr, Wt1h, Wt1l, nullptr, hw, NNODES);
  // h1 (into h0 buffer) = relu(agg(hw) + hw*dinv + b1)
  int gA=(NNODES+3)/4;
  k_agg_h<<<gA,256,0,stream>>>((const uint4*)hw, rp, esrc, dis, dinv, b1, (uint4*)h0);
  // hw2 (into hw buffer) = h1 @ W2
  k_mm40<<<gM,256,0,stream>>>(h0, Wt2h, Wt2l, hw, NNODES);
  // out = agg(hw2) + hw2*dinv + b2
  k_agg_out<<<gA,256,0,stream>>>((const uint2*)hw, rp, esrc, dis, dinv, b2, out);
}

// Round 9
// 464.283 us; speedup vs baseline: 1.1900x; 1.0182x over previous
//
#include <hip/hip_runtime.h>
#include <cstdint>
#include <cstddef>

#define NNODES 100000
#define NEDGES 1600000
#define INCH   128
#define HID    128
#define NCLS   40
#define NCOMM_ 1000

#define NBLK  128                 // partition blocks for bucket sort
#define EPB   (NEDGES/NBLK)       // 12500 edges per block (exact)
#define NBUCK ((NNODES+255)/256)  // 391 buckets of 256 nodes
#define NCNT  (NBLK*NBUCK)

typedef unsigned int uint32;
typedef unsigned short ushort16;
typedef short s16x8 __attribute__((ext_vector_type(8)));
typedef float f32x4 __attribute__((ext_vector_type(4)));
typedef float f32x2 __attribute__((ext_vector_type(2)));

static __device__ __forceinline__ float4 ld4(const float* p){ return *reinterpret_cast<const float4*>(p); }

// f32 -> bf16 (RTN-even) and back, via bit ops
static __device__ __forceinline__ unsigned short f2b(float f){
  union{float f; uint32 u;} v; v.f=f;
  uint32 r = v.u + 0x7fffu + ((v.u>>16)&1u);
  return (unsigned short)(r>>16);
}
static __device__ __forceinline__ float b2f(unsigned short h){
  union{uint32 u; float f;} v; v.u = ((uint32)h)<<16; return v.f;
}
static __device__ __forceinline__ float lo16f(uint32 u){ return __int_as_float((int)(u<<16)); }
static __device__ __forceinline__ float hi16f(uint32 u){ return __int_as_float((int)(u&0xffff0000u)); }

// unpack u32 (2 bf16) -> f32x2 {lo, hi}
static __device__ __forceinline__ f32x2 up2(uint32 u){
  union{uint2 u2; f32x2 f;} c;
  c.u2.x = u<<16; c.u2.y = u&0xffff0000u;
  return c.f;
}
// a[4] f32x2 covers 8 feats; packed fma (v_pk_fma_f32)
static __device__ __forceinline__ void acc8p(f32x2* a, uint4 v, float nr){
  f32x2 n; n[0]=nr; n[1]=nr;
  a[0] += up2(v.x)*n;
  a[1] += up2(v.y)*n;
  a[2] += up2(v.z)*n;
  a[3] += up2(v.w)*n;
}
static __device__ __forceinline__ void acc4p(f32x2* a, uint2 v, float nr){
  f32x2 n; n[0]=nr; n[1]=nr;
  a[0] += up2(v.x)*n;
  a[1] += up2(v.y)*n;
}

// ---------------- community counting (atomics; only 100K over 1000 bins) ----------------
__global__ void k_ccomm(const int* __restrict__ comm, int* __restrict__ ccnt){
  int i=blockIdx.x*blockDim.x+threadIdx.x;
  if(i<NNODES) atomicAdd(&ccnt[comm[i]],1);
}

// ---------------- x -> bf16 (identical rounding to previous inline path) ----------------
__global__ __launch_bounds__(256) void k_xprep(const float* __restrict__ x, ushort16* __restrict__ xb){
  size_t i=(size_t)(blockIdx.x*256u+threadIdx.x)*8u;
  if(i>=(size_t)NNODES*INCH) return;
  float4 p0=ld4(x+i), p1=ld4(x+i+4);
  s16x8 q;
  q[0]=(short)f2b(p0.x); q[1]=(short)f2b(p0.y); q[2]=(short)f2b(p0.z); q[3]=(short)f2b(p0.w);
  q[4]=(short)f2b(p1.x); q[5]=(short)f2b(p1.y); q[6]=(short)f2b(p1.z); q[7]=(short)f2b(p1.w);
  *(s16x8*)(xb+i)=q;
}

// ---------------- bucket sort pass A: per-block LDS histogram over dst>>8 ----------------
__global__ __launch_bounds__(256) void k_bcnt(const int* __restrict__ ei, int* __restrict__ cnt){
  __shared__ int h[NBUCK];
  int t=threadIdx.x, blk=blockIdx.x;
  for(int i=t;i<NBUCK;i+=256) h[i]=0;
  __syncthreads();
  int base=blk*EPB;
  for(int j=t;j<EPB;j+=256){
    int d=ei[NEDGES+base+j];
    atomicAdd(&h[d>>8],1);
  }
  __syncthreads();
  for(int i=t;i<NBUCK;i+=256) cnt[i*NBLK+blk]=h[i];
}

// ---------------- generic 3-phase exclusive scan ----------------
__global__ void k_scan1(const int* __restrict__ in, int n, int* __restrict__ part){
  int t=threadIdx.x, b=blockIdx.x;
  int base=b*1024+t*4, s=0;
  #pragma unroll
  for(int j=0;j<4;j++){ int i=base+j; if(i<n) s+=in[i]; }
  #pragma unroll
  for(int off=32;off>0;off>>=1) s+=__shfl_down(s,off,64);
  __shared__ int wm[4];
  if((t&63)==0) wm[t>>6]=s;
  __syncthreads();
  if(t==0) part[b]=wm[0]+wm[1]+wm[2]+wm[3];
}

__global__ void k_scan2(int* __restrict__ part, int P){
  __shared__ int sm[256];
  int t=threadIdx.x;
  int v=(t<P)?part[t]:0;
  sm[t]=v; __syncthreads();
  #pragma unroll
  for(int off=1;off<256;off<<=1){
    int u=(t>=off)?sm[t-off]:0;
    __syncthreads();
    sm[t]+=u;
    __syncthreads();
  }
  if(t<P) part[t]=(t==0)?0:sm[t-1];
  if(t==0) part[P]=sm[255];
}

__global__ void k_scan3(const int* __restrict__ in, int n, const int* __restrict__ part, int P,
                        int* __restrict__ out){
  int t=threadIdx.x,b=blockIdx.x;
  int base=b*1024+t*4;
  int v[4], ts=0;
  #pragma unroll
  for(int j=0;j<4;j++){ v[j]=(base+j<n)?in[base+j]:0; ts+=v[j]; }
  int lane=t&63, w=t>>6, sc=ts;
  #pragma unroll
  for(int off=1;off<64;off<<=1){ int u=__shfl_up(sc,off,64); if(lane>=off) sc+=u; }
  __shared__ int wm[4];
  if(lane==63) wm[w]=sc;
  __syncthreads();
  int woff=0;
  for(int i=0;i<w;i++) woff+=wm[i];
  int pos=part[b]+woff+sc-ts;
  #pragma unroll
  for(int j=0;j<4;j++){ if(base+j<n) out[base+j]=pos; pos+=v[j]; }
  if(b==0 && t==0) out[n]=part[P];
}

// ---------------- extract bucket bases from scanned cnt ----------------
__global__ void k_bextract(const int* __restrict__ cntx, int* __restrict__ brow, int* __restrict__ rp){
  int b=blockIdx.x*blockDim.x+threadIdx.x;
  if(b<NBUCK) brow[b]=cntx[b*NBLK];
  if(b==NBUCK){ brow[NBUCK]=NEDGES; rp[NNODES]=NEDGES; }
}

// ---------------- bucket sort pass C: deterministic scatter (packed u32 records) ----------------
// rec = s | (d&255)<<17   (s < 2^17)
__global__ __launch_bounds__(256) void k_bscatter(const int* __restrict__ ei, const int* __restrict__ cntx,
                                                  uint32* __restrict__ ebuf){
  __shared__ int offs[NBUCK];
  int t=threadIdx.x, blk=blockIdx.x;
  for(int i=t;i<NBUCK;i+=256) offs[i]=cntx[i*NBLK+blk];
  __syncthreads();
  int base=blk*EPB;
  for(int j=t;j<EPB;j+=256){
    int e=base+j;
    int s=ei[e], d=ei[NEDGES+e];
    int p=atomicAdd(&offs[d>>8],1);
    ebuf[p]=(uint32)s | (((uint32)d&255u)<<17);
  }
}

// ---------------- bucket sort pass D: per-bucket CSR (rp, dis, dinv, esrc) ----------------
__global__ __launch_bounds__(256) void k_bcsr(const uint32* __restrict__ ebuf, const int* __restrict__ brow,
                                              int* __restrict__ rp, float* __restrict__ dis,
                                              float* __restrict__ dinv, int* __restrict__ esrc){
  __shared__ int lcnt[256], lrp[256], lfill[256];
  int b=blockIdx.x, t=threadIdx.x;
  int e0=brow[b], e1=brow[b+1];
  int n0=b*256, nloc=min(256, NNODES-n0);
  lcnt[t]=0;
  __syncthreads();
  for(int e=e0+t;e<e1;e+=256){
    atomicAdd(&lcnt[ebuf[e]>>17],1);
  }
  __syncthreads();
  lrp[t]=lcnt[t]; __syncthreads();
  #pragma unroll
  for(int off=1;off<256;off<<=1){
    int u=(t>=off)?lrp[t-off]:0;
    __syncthreads();
    lrp[t]+=u;
    __syncthreads();
  }
  int excl=lrp[t]-lcnt[t];
  __syncthreads();
  lrp[t]=e0+excl;      // absolute segment base
  lfill[t]=0;
  if(t<nloc){
    int gid=n0+t;
    rp[gid]=e0+excl;
    float dd=(float)(lcnt[t]+1);
    dis[gid]=rsqrtf(dd);
    dinv[gid]=1.0f/dd;
  }
  __syncthreads();
  for(int e=e0+t;e<e1;e+=256){
    uint32 r=ebuf[e];
    int lr=r>>17;
    int slot=atomicAdd(&lfill[lr],1);
    esrc[lrp[lr]+slot]=(int)(r&0x1ffffu);
  }
}

__global__ void k_fill_comm(const int* __restrict__ comm, const int* __restrict__ crow, int* __restrict__ cfill,
                            int* __restrict__ cnode){
  int i=blockIdx.x*blockDim.x+threadIdx.x;
  if(i<NNODES){
    int c=comm[i];
    int p=crow[c]+atomicAdd(&cfill[c],1);
    cnode[p]=i;
  }
}

// ---------------- community mean (f32 accumulate, bf16 out) ----------------
__global__ void k_comm_mean(const float* __restrict__ x, const int* __restrict__ crow,
                            const int* __restrict__ cnode, ushort16* __restrict__ cmb){
  int c=blockIdx.x; int f=threadIdx.x; // 128 threads
  int a=crow[c], b=crow[c+1];
  float s=0.f;
  for(int j=a;j<b;j++){
    int nd=cnode[j];
    s += x[(size_t)nd*INCH + f];
  }
  float cnt=(float)(b-a);
  cmb[(size_t)c*INCH + f] = f2b(s / fmaxf(cnt,1.0f));
}

// ---------------- weight prep: split f32 W[K][N] into transposed bf16 hi/lo planes [N][K] ----------------
__global__ void k_wprep(const float* __restrict__ W_in, const float* __restrict__ W1, const float* __restrict__ W2,
                        ushort16* __restrict__ Wt0h, ushort16* __restrict__ Wt0l,
                        ushort16* __restrict__ Wt1h, ushort16* __restrict__ Wt1l,
                        ushort16* __restrict__ Wt2h, ushort16* __restrict__ Wt2l){
  int t = blockIdx.x*256 + threadIdx.x;
  float v; ushort16* ph; ushort16* pl; int off;
  if(t < 32768){            // W_in: [256][128] -> Wt0[n=128][k=256]
    int n=t>>8, k=t&255; v=W_in[k*128+n]; ph=Wt0h; pl=Wt0l; off=t;
  } else if(t < 49152){     // W1: [128][128] -> Wt1[128][128]
    int u=t-32768; int n=u>>7, k=u&127; v=W1[k*128+n]; ph=Wt1h; pl=Wt1l; off=u;
  } else if(t < 55296){     // W2: [128][40] -> Wt2[48][128], rows 40..47 zero
    int u=t-49152; int n=u>>7, k=u&127; v=(n<40)?W2[k*40+n]:0.f; ph=Wt2h; pl=Wt2l; off=u;
  } else return;
  unsigned short h=f2b(v); unsigned short lo=f2b(v-b2f(h));
  ph[off]=h; pl[off]=lo;
}

// ---------------- MFMA GEMM: out[M][128](bf16) = A[M][K] @ W + (bias, relu) ----------------
// CONCAT: A = [xb | cmb[comm]] bf16, K=256.  else: A = bf16 [M][K].
template<int K, bool CONCAT, bool BIAS, bool RELU>
__global__ __launch_bounds__(256) void k_mm128(const ushort16* __restrict__ A0, const ushort16* __restrict__ A1,
                                               const int* __restrict__ comm,
                                               const ushort16* __restrict__ WtH, const ushort16* __restrict__ WtL,
                                               const float* __restrict__ bias,
                                               ushort16* __restrict__ out, int M){
  __shared__ __align__(16) ushort16 As[128*40];   // row stride 40 ushorts (80B): 2-way bank alias only
  __shared__ __align__(16) ushort16 Bh[128*40];
  __shared__ __align__(16) ushort16 Bl[128*40];
  int t=threadIdx.x;
  int m0=blockIdx.x*128;
  int lane=t&63, w=t>>6;
  int g=lane>>4, r15=lane&15;

  f32x4 acc0[8], acc1[8];
  #pragma unroll
  for(int i=0;i<8;i++){ acc0[i]=(f32x4){0,0,0,0}; acc1[i]=(f32x4){0,0,0,0}; }

  int ar = t>>1, ko = (t&1)*16;     // staging coords: row, k-offset(16 elems)
  int gr = m0 + ar;
  int cm = (CONCAT && gr<M) ? comm[gr] : 0;

  for(int kc=0;kc<K;kc+=32){
    __syncthreads();
    // ---- stage A chunk: 128 x 32 bf16 (pure vector loads) ----
    {
      s16x8 q0, q1;
      if(gr < M){
        const ushort16* srcu;
        if(CONCAT){
          srcu = (kc<128) ? (A0 + (size_t)gr*128 + kc + ko)
                          : (A1 + (size_t)cm*128 + (kc-128) + ko);
        } else {
          srcu = A0 + (size_t)gr*K + kc + ko;
        }
        q0 = *(const s16x8*)srcu;
        q1 = *(const s16x8*)(srcu+8);
      } else {
        q0=(s16x8){0,0,0,0,0,0,0,0}; q1=q0;
      }
      ushort16* dst=&As[ar*40+ko];
      *(s16x8*)dst=q0; *(s16x8*)(dst+8)=q1;
    }
    // ---- stage B chunk: hi & lo planes ----
    {
      const ushort16* sh=&WtH[(size_t)ar*K + kc + ko];
      s16x8 b0=*(const s16x8*)sh, b1=*(const s16x8*)(sh+8);
      ushort16* dh=&Bh[ar*40+ko];
      *(s16x8*)dh=b0; *(s16x8*)(dh+8)=b1;
      const ushort16* sl=&WtL[(size_t)ar*K + kc + ko];
      s16x8 c0=*(const s16x8*)sl, c1=*(const s16x8*)(sl+8);
      ushort16* dl=&Bl[ar*40+ko];
      *(s16x8*)dl=c0; *(s16x8*)(dl+8)=c1;
    }
    __syncthreads();
    s16x8 a0 = *(const s16x8*)&As[(w*32      + r15)*40 + g*8];
    s16x8 a1 = *(const s16x8*)&As[(w*32 + 16 + r15)*40 + g*8];
    #pragma unroll
    for(int tn=0;tn<8;tn++){
      s16x8 bh = *(const s16x8*)&Bh[(tn*16 + r15)*40 + g*8];
      s16x8 bl = *(const s16x8*)&Bl[(tn*16 + r15)*40 + g*8];
      acc0[tn] = __builtin_amdgcn_mfma_f32_16x16x32_bf16(a0, bh, acc0[tn], 0,0,0);
      acc0[tn] = __builtin_amdgcn_mfma_f32_16x16x32_bf16(a0, bl, acc0[tn], 0,0,0);
      acc1[tn] = __builtin_amdgcn_mfma_f32_16x16x32_bf16(a1, bh, acc1[tn], 0,0,0);
      acc1[tn] = __builtin_amdgcn_mfma_f32_16x16x32_bf16(a1, bl, acc1[tn], 0,0,0);
    }
  }

  #pragma unroll
  for(int tn=0;tn<8;tn++){
    int col = tn*16 + r15;
    float bv = BIAS ? bias[col] : 0.f;
    #pragma unroll
    for(int rr=0;rr<4;rr++){
      int row0 = m0 + w*32 + g*4 + rr;
      if(row0 < M){
        float v = acc0[tn][rr] + bv;
        if(RELU) v = fmaxf(v, 0.f);
        out[(size_t)row0*128 + col] = f2b(v);
      }
      int row1 = m0 + w*32 + 16 + g*4 + rr;
      if(row1 < M){
        float v = acc1[tn][rr] + bv;
        if(RELU) v = fmaxf(v, 0.f);
        out[(size_t)row1*128 + col] = f2b(v);
      }
    }
  }
}

// ---------------- MFMA GEMM: hw2[M][40](bf16) = h1[M][128](bf16) @ W2 ----------------
__global__ __launch_bounds__(256) void k_mm40(const ushort16* __restrict__ A0,
                                              const ushort16* __restrict__ WtH, const ushort16* __restrict__ WtL,
                                              ushort16* __restrict__ out, int M){
  __shared__ __align__(16) ushort16 As[128*40];
  __shared__ __align__(16) ushort16 Bh[48*40];
  __shared__ __align__(16) ushort16 Bl[48*40];
  int t=threadIdx.x;
  int m0=blockIdx.x*128;
  int lane=t&63, w=t>>6;
  int g=lane>>4, r15=lane&15;

  f32x4 acc0[3], acc1[3];
  #pragma unroll
  for(int i=0;i<3;i++){ acc0[i]=(f32x4){0,0,0,0}; acc1[i]=(f32x4){0,0,0,0}; }

  int ar=t>>1, ko=(t&1)*16;

  for(int kc=0;kc<128;kc+=32){
    __syncthreads();
    {
      s16x8 q0,q1;
      int gr=m0+ar;
      if(gr<M){
        const ushort16* srcu = A0 + (size_t)gr*128 + kc + ko;
        q0=*(const s16x8*)srcu; q1=*(const s16x8*)(srcu+8);
      } else { q0=(s16x8){0,0,0,0,0,0,0,0}; q1=q0; }
      ushort16* dst=&As[ar*40+ko];
      *(s16x8*)dst=q0; *(s16x8*)(dst+8)=q1;
    }
    if(t<96){
      int n=t>>1, k2=(t&1)*16;
      const ushort16* sh=&WtH[(size_t)n*128 + kc + k2];
      s16x8 b0=*(const s16x8*)sh, b1=*(const s16x8*)(sh+8);
      ushort16* dh=&Bh[n*40+k2];
      *(s16x8*)dh=b0; *(s16x8*)(dh+8)=b1;
    } else if(t<192){
      int u=t-96; int n=u>>1, k2=(u&1)*16;
      const ushort16* sl=&WtL[(size_t)n*128 + kc + k2];
      s16x8 c0=*(const s16x8*)sl, c1=*(const s16x8*)(sl+8);
      ushort16* dl=&Bl[n*40+k2];
      *(s16x8*)dl=c0; *(s16x8*)(dl+8)=c1;
    }
    __syncthreads();
    s16x8 a0=*(const s16x8*)&As[(w*32      + r15)*40 + g*8];
    s16x8 a1=*(const s16x8*)&As[(w*32 + 16 + r15)*40 + g*8];
    #pragma unroll
    for(int tn=0;tn<3;tn++){
      s16x8 bh=*(const s16x8*)&Bh[(tn*16 + r15)*40 + g*8];
      s16x8 bl=*(const s16x8*)&Bl[(tn*16 + r15)*40 + g*8];
      acc0[tn]=__builtin_amdgcn_mfma_f32_16x16x32_bf16(a0,bh,acc0[tn],0,0,0);
      acc0[tn]=__builtin_amdgcn_mfma_f32_16x16x32_bf16(a0,bl,acc0[tn],0,0,0);
      acc1[tn]=__builtin_amdgcn_mfma_f32_16x16x32_bf16(a1,bh,acc1[tn],0,0,0);
      acc1[tn]=__builtin_amdgcn_mfma_f32_16x16x32_bf16(a1,bl,acc1[tn],0,0,0);
    }
  }
  #pragma unroll
  for(int tn=0;tn<3;tn++){
    int col=tn*16+r15;
    if(col<NCLS){
      #pragma unroll
      for(int rr=0;rr<4;rr++){
        int row0=m0+w*32+g*4+rr;
        if(row0<M) out[(size_t)row0*NCLS+col]=f2b(acc0[tn][rr]);
        int row1=m0+w*32+16+g*4+rr;
        if(row1<M) out[(size_t)row1*NCLS+col]=f2b(acc1[tn][rr]);
      }
    }
  }
}

// ---------------- aggregation layer1: 4 waves/block (1 node each); 4 edge-groups x 16 lanes ----------------
// lane f covers feats [8f,8f+7] via one uint4. Unroll 4 -> 16 row-gathers in flight per wave.
__global__ __launch_bounds__(256) void k_agg_h(const uint4* __restrict__ hwv, const int* __restrict__ rp,
                                               const int* __restrict__ esrc,
                                               const float* __restrict__ dis, const float* __restrict__ dinv,
                                               const float* __restrict__ bias, uint4* __restrict__ h1v){
  int w=threadIdx.x>>6;
  int i=blockIdx.x*4+w;
  if(i>=NNODES) return;
  int lane=threadIdx.x&63;
  int g=lane>>4, f=lane&15;
  int e0=rp[i], e1=rp[i+1];
  float di=dis[i];
  f32x2 a[4];
  a[0]=(f32x2){0,0}; a[1]=(f32x2){0,0}; a[2]=(f32x2){0,0}; a[3]=(f32x2){0,0};
  int e=e0+g;
  for(; e+12<e1; e+=16){
    int s0=esrc[e], s1=esrc[e+4], s2=esrc[e+8], s3=esrc[e+12];
    float n0=di*dis[s0], n1=di*dis[s1], n2=di*dis[s2], n3=di*dis[s3];
    uint4 v0=hwv[(size_t)s0*16+f];
    uint4 v1=hwv[(size_t)s1*16+f];
    uint4 v2=hwv[(size_t)s2*16+f];
    uint4 v3=hwv[(size_t)s3*16+f];
    acc8p(a,v0,n0); acc8p(a,v1,n1); acc8p(a,v2,n2); acc8p(a,v3,n3);
  }
  for(; e<e1; e+=4){
    int s0=esrc[e];
    float n0=di*dis[s0];
    uint4 v0=hwv[(size_t)s0*16+f];
    acc8p(a,v0,n0);
  }
  float* af=(float*)a;
  #pragma unroll
  for(int k=0;k<8;k++){
    af[k]+=__shfl_xor(af[k],16);
    af[k]+=__shfl_xor(af[k],32);
  }
  if(g==0){
    uint4 sv=hwv[(size_t)i*16+f];
    float dv=dinv[i];
    float4 bA=*reinterpret_cast<const float4*>(&bias[8*f]);
    float4 bB=*reinterpret_cast<const float4*>(&bias[8*f+4]);
    float o0=fmaxf(fmaf(lo16f(sv.x),dv,af[0])+bA.x,0.f);
    float o1=fmaxf(fmaf(hi16f(sv.x),dv,af[1])+bA.y,0.f);
    float o2=fmaxf(fmaf(lo16f(sv.y),dv,af[2])+bA.z,0.f);
    float o3=fmaxf(fmaf(hi16f(sv.y),dv,af[3])+bA.w,0.f);
    float o4=fmaxf(fmaf(lo16f(sv.z),dv,af[4])+bB.x,0.f);
    float o5=fmaxf(fmaf(hi16f(sv.z),dv,af[5])+bB.y,0.f);
    float o6=fmaxf(fmaf(lo16f(sv.w),dv,af[6])+bB.z,0.f);
    float o7=fmaxf(fmaf(hi16f(sv.w),dv,af[7])+bB.w,0.f);
    uint4 o;
    o.x=((uint32)f2b(o1)<<16)|(uint32)f2b(o0);
    o.y=((uint32)f2b(o3)<<16)|(uint32)f2b(o2);
    o.z=((uint32)f2b(o5)<<16)|(uint32)f2b(o4);
    o.w=((uint32)f2b(o7)<<16)|(uint32)f2b(o6);
    h1v[(size_t)i*16+f]=o;
  }
}

// ---------------- aggregation layer2: 4 waves/block; 4 edge-groups x 16 lanes (10 active) ----------------
__global__ __launch_bounds__(256) void k_agg_out(const uint2* __restrict__ hv, const int* __restrict__ rp,
                                                 const int* __restrict__ esrc,
                                                 const float* __restrict__ dis, const float* __restrict__ dinv,
                                                 const float* __restrict__ bias, float* __restrict__ out){
  int w=threadIdx.x>>6;
  int i=blockIdx.x*4+w;
  if(i>=NNODES) return;
  int lane=threadIdx.x&63;
  int g=lane>>4, f=lane&15;
  bool act=(f<10);
  int e0=rp[i], e1=rp[i+1];
  float di=dis[i];
  f32x2 a[2];
  a[0]=(f32x2){0,0}; a[1]=(f32x2){0,0};
  int e=e0+g;
  for(; e+12<e1; e+=16){
    int s0=esrc[e], s1=esrc[e+4], s2=esrc[e+8], s3=esrc[e+12];
    float n0=di*dis[s0], n1=di*dis[s1], n2=di*dis[s2], n3=di*dis[s3];
    if(act){
      uint2 v0=hv[(size_t)s0*10+f];
      uint2 v1=hv[(size_t)s1*10+f];
      uint2 v2=hv[(size_t)s2*10+f];
      uint2 v3=hv[(size_t)s3*10+f];
      acc4p(a,v0,n0); acc4p(a,v1,n1); acc4p(a,v2,n2); acc4p(a,v3,n3);
    }
  }
  for(; e<e1; e+=4){
    int s0=esrc[e];
    float n0=di*dis[s0];
    if(act){
      uint2 v0=hv[(size_t)s0*10+f];
      acc4p(a,v0,n0);
    }
  }
  float* af=(float*)a;
  #pragma unroll
  for(int k=0;k<4;k++){
    af[k]+=__shfl_xor(af[k],16);
    af[k]+=__shfl_xor(af[k],32);
  }
  if(g==0 && act){
    uint2 sv=hv[(size_t)i*10+f];
    float dv=dinv[i];
    float4 b=*reinterpret_cast<const float4*>(&bias[4*f]);
    float4 o;
    o.x=fmaf(lo16f(sv.x),dv,af[0])+b.x;
    o.y=fmaf(hi16f(sv.x),dv,af[1])+b.y;
    o.z=fmaf(lo16f(sv.y),dv,af[2])+b.z;
    o.w=fmaf(hi16f(sv.y),dv,af[3])+b.w;
    *reinterpret_cast<float4*>(&out[(size_t)i*40+4*f])=o;
  }
}

// ---------------- launcher ----------------
extern "C" void kernel_launch(void* const* d_in, const int* in_sizes, int n_in,
                              void* d_out, int out_size, void* d_ws, size_t ws_size,
                              hipStream_t stream) {
  const float* x    = (const float*)d_in[0];
  const int*   ei   = (const int*)  d_in[1];
  const int*   comm = (const int*)  d_in[2];
  const float* W_in = (const float*)d_in[3];
  const float* b_in = (const float*)d_in[4];
  const float* W1   = (const float*)d_in[5];
  const float* b1   = (const float*)d_in[6];
  const float* W2   = (const float*)d_in[7];
  const float* b2   = (const float*)d_in[8];
  float* out = (float*)d_out;

  char* base=(char*)d_ws; size_t off=0;
  auto alloc=[&](size_t bytes)->void*{ void* p=base+off; off=(off+bytes+255)&~(size_t)255; return p; };

  // zero zone: ccnt, cfill
  int* zz    =(int*)alloc((size_t)(2*NCOMM_)*4);
  int* ccnt  = zz;
  int* cfill = zz + NCOMM_;
  int* cnt   =(int*)alloc((size_t)NCNT*4);
  int* cntx  =(int*)alloc((size_t)(NCNT+1)*4);
  int* partA =(int*)alloc(64*4);
  int* brow  =(int*)alloc((size_t)(NBUCK+1)*4);
  int* rp    =(int*)alloc((size_t)(NNODES+1)*4);
  int* crow  =(int*)alloc((size_t)(NCOMM_+1)*4);
  int* partB =(int*)alloc(16*4);
  uint32* ebuf=(uint32*)alloc((size_t)NEDGES*4);
  int* esrc  =(int*)alloc((size_t)NEDGES*4);
  int* cnode =(int*)alloc((size_t)NNODES*4);
  float* dis =(float*)alloc((size_t)NNODES*4);
  float* dinv=(float*)alloc((size_t)NNODES*4);
  ushort16* xb  =(ushort16*)alloc((size_t)NNODES*INCH*2);
  ushort16* cmb =(ushort16*)alloc((size_t)NCOMM_*INCH*2);
  ushort16* h0 =(ushort16*)alloc((size_t)NNODES*HID*2);   // bf16; reused as h1
  ushort16* hw =(ushort16*)alloc((size_t)NNODES*HID*2);   // bf16; reused as hw2
  ushort16* Wt0h=(ushort16*)alloc(32768*2);
  ushort16* Wt0l=(ushort16*)alloc(32768*2);
  ushort16* Wt1h=(ushort16*)alloc(16384*2);
  ushort16* Wt1l=(ushort16*)alloc(16384*2);
  ushort16* Wt2h=(ushort16*)alloc(6144*2);
  ushort16* Wt2l=(ushort16*)alloc(6144*2);

  hipMemsetAsync(zz, 0, (size_t)(2*NCOMM_)*4, stream);

  int gN=(NNODES+255)/256;

  // ---- CSR build via deterministic bucket sort (no global atomics) ----
  k_bcnt    <<<NBLK,256,0,stream>>>(ei, cnt);
  int PC=(NCNT+1023)/1024;   // 49 blocks
  k_scan1<<<PC,256,0,stream>>>(cnt, NCNT, partA);
  k_scan2<<<1,256,0,stream>>>(partA, PC);
  k_scan3<<<PC,256,0,stream>>>(cnt, NCNT, partA, PC, cntx);
  k_bextract<<<(NBUCK+256)/256,256,0,stream>>>(cntx, brow, rp);
  k_bscatter<<<NBLK,256,0,stream>>>(ei, cntx, ebuf);
  k_bcsr    <<<NBUCK,256,0,stream>>>(ebuf, brow, rp, dis, dinv, esrc);

  // ---- x -> bf16 ----
  k_xprep<<<6250,256,0,stream>>>(x, xb);

  // ---- community CSR (small; atomics fine) ----
  k_ccomm<<<gN,256,0,stream>>>(comm, ccnt);
  int PB=(NCOMM_+1023)/1024;   // 1
  k_scan1<<<PB,256,0,stream>>>(ccnt, NCOMM_, partB);
  k_scan2<<<1,256,0,stream>>>(partB, PB);
  k_scan3<<<PB,256,0,stream>>>(ccnt, NCOMM_, partB, PB, crow);
  k_fill_comm<<<gN,256,0,stream>>>(comm, crow, cfill, cnode);
  k_comm_mean<<<NCOMM_,128,0,stream>>>(x, crow, cnode, cmb);
  k_wprep<<<216,256,0,stream>>>(W_in, W1, W2, Wt0h, Wt0l, Wt1h, Wt1l, Wt2h, Wt2l);

  int gM=(NNODES+127)/128;
  // h0 = relu([xb | cmb[comm]] @ W_in + b_in)   (bf16 out)
  k_mm128<256,true,true,true><<<gM,256,0,stream>>>(xb, cmb, comm, Wt0h, Wt0l, b_in, h0, NNODES);
  // hw = h0 @ W1  (bf16 out)
  k_mm128<128,false,false,false><<<gM,256,0,stream>>>(h0, nullptr, nullptr, Wt1h, Wt1l, nullptr, hw, NNODES);
  // h1 (into h0 buffer) = relu(agg(hw) + hw*dinv + b1)
  int gA=(NNODES+3)/4;
  k_agg_h<<<gA,256,0,stream>>>((const uint4*)hw, rp, esrc, dis, dinv, b1, (uint4*)h0);
  // hw2 (into hw buffer) = h1 @ W2
  k_mm40<<<gM,256,0,stream>>>(h0, Wt2h, Wt2l, hw, NNODES);
  // out = agg(hw2) + hw2*dinv + b2
  k_agg_out<<<gA,256,0,stream>>>((const uint2*)hw, rp, esrc, dis, dinv, b2, out);
}